// Round 1
// baseline (701.320 us; speedup 1.0000x reference)
//
#include <hip/hip_runtime.h>
#include <stdint.h>

#define NN 100000
#define D 128

// ---- workspace layout (bytes) ----
static const size_t O_FLAG = 0;
static const size_t O_WTL  = 256;
static const size_t O_WTR  = O_WTL + (size_t)D * D * 4;
static const size_t O_DEG  = O_WTR + (size_t)D * D * 4;     // Plan B only
static const size_t O_OFFS = O_DEG + (size_t)NN * 4;
static const size_t O_CURS = O_OFFS + (size_t)(NN + 1) * 4;
static const size_t O_SRCS = O_CURS + (size_t)NN * 4;

// Detect whether edge_index buffer is int64 (odd int32 words zero) or int32.
__global__ void k_detect(const int* __restrict__ ei, int* flag) {
    if (threadIdx.x == 0 && blockIdx.x == 0) {
        int ok = 1;
        for (int j = 0; j < 128; ++j)
            if (ei[2 * j + 1] != 0) { ok = 0; break; }
        *flag = ok;
    }
}

__device__ __forceinline__ int edge_at(const int* ei, long long pos, int is64) {
    return is64 ? ei[2 * pos] : ei[pos];
}

// Transpose both weight matrices: Wt[k][o] = W[o][k]
__global__ void k_transpose(const float* __restrict__ Wl, const float* __restrict__ Wr,
                            float* __restrict__ WtL, float* __restrict__ WtR) {
    int t = blockIdx.x * 256 + threadIdx.x;
    if (t < D * D) {
        int o = t >> 7, k = t & 127;
        WtL[k * D + o] = Wl[t];
        WtR[k * D + o] = Wr[t];
    }
}

// Histogram of dst into offs[d+1]
__global__ void k_hist(const int* __restrict__ ei, const int* __restrict__ flag,
                       int* __restrict__ offs, long long E) {
    long long i = (long long)blockIdx.x * 256 + threadIdx.x;
    if (i >= E) return;
    int is64 = *flag;
    int d = edge_at(ei, E + i, is64);
    atomicAdd(&offs[d + 1], 1);
}

// Single-block inclusive scan over M ints (M = NN+1)
__global__ __launch_bounds__(1024) void k_scan(int* __restrict__ a, int M) {
    __shared__ int part[1024];
    int t = threadIdx.x;
    int chunk = (M + 1023) >> 10;
    int base = t * chunk;
    int end = base + chunk; if (end > M) end = M;
    int s = 0;
    for (int i = base; i < end; ++i) s += a[i];
    part[t] = s;
    __syncthreads();
    for (int dstep = 1; dstep < 1024; dstep <<= 1) {
        int v = (t >= dstep) ? part[t - dstep] : 0;
        __syncthreads();
        part[t] += v;
        __syncthreads();
    }
    int running = (t > 0) ? part[t - 1] : 0;
    for (int i = base; i < end; ++i) {
        running += a[i];
        a[i] = running;
    }
}

// Fill CSR adjacency: srcs[offs[d] + cursor[d]++] = src
__global__ void k_fill(const int* __restrict__ ei, const int* __restrict__ flag,
                       const int* __restrict__ offs, int* __restrict__ curs,
                       int* __restrict__ srcs, long long E) {
    long long i = (long long)blockIdx.x * 256 + threadIdx.x;
    if (i >= E) return;
    int is64 = *flag;
    int s = edge_at(ei, i, is64);
    int d = edge_at(ei, E + i, is64);
    int pos = offs[d] + atomicAdd(&curs[d], 1);
    srcs[pos] = s;
}

// One wave per node: mean-aggregate neighbor rows. Writes agg into `agg` (= d_out).
__global__ __launch_bounds__(256) void k_agg(const float* __restrict__ x,
                                             const int* __restrict__ offs,
                                             const int* __restrict__ srcs,
                                             float* agg, int N) {
    int lane = threadIdx.x & 63;
    int wid = __builtin_amdgcn_readfirstlane(threadIdx.x >> 6);
    int node = blockIdx.x * 4 + wid;
    if (node >= N) return;
    int e0 = offs[node], e1 = offs[node + 1];
    const float2* x2 = (const float2*)x;
    float ax = 0.f, ay = 0.f;
    int e = e0;
    for (; e + 4 <= e1; e += 4) {
        int s0 = srcs[e], s1 = srcs[e + 1], s2 = srcs[e + 2], s3 = srcs[e + 3];
        float2 v0 = x2[(long long)s0 * 64 + lane];
        float2 v1 = x2[(long long)s1 * 64 + lane];
        float2 v2 = x2[(long long)s2 * 64 + lane];
        float2 v3 = x2[(long long)s3 * 64 + lane];
        ax += v0.x + v1.x + v2.x + v3.x;
        ay += v0.y + v1.y + v2.y + v3.y;
    }
    for (; e < e1; ++e) {
        int s = srcs[e];
        float2 v = x2[(long long)s * 64 + lane];
        ax += v.x; ay += v.y;
    }
    float inv = 1.0f / fmaxf((float)(e1 - e0), 1.0f);
    float2 o; o.x = ax * inv; o.y = ay * inv;
    ((float2*)agg)[(long long)node * 64 + lane] = o;
}

// Plan B: atomic scatter (one wave per edge) then mean.
__global__ __launch_bounds__(256) void k_scatterB(const float* __restrict__ x,
                                                  const int* __restrict__ ei,
                                                  const int* __restrict__ flag,
                                                  float* out, float* deg, long long E) {
    int lane = threadIdx.x & 63;
    long long e = (long long)blockIdx.x * 4 + (threadIdx.x >> 6);
    if (e >= E) return;
    int is64 = *flag;
    int s = edge_at(ei, e, is64);
    int d = edge_at(ei, E + e, is64);
    atomicAdd(&out[(long long)d * D + lane], x[(long long)s * D + lane]);
    atomicAdd(&out[(long long)d * D + 64 + lane], x[(long long)s * D + 64 + lane]);
    if (lane == 0) atomicAdd(&deg[d], 1.0f);
}

__global__ void k_meanB(float* out, const float* __restrict__ deg) {
    long long i = (long long)blockIdx.x * 256 + threadIdx.x;
    if (i >= (long long)NN * D) return;
    out[i] *= 1.0f / fmaxf(deg[i >> 7], 1.0f);
}

// Fused out = agg@Wl^T + b + x@Wr^T, then row L2-normalize. In-place on agg==out:
// all agg reads happen before the __syncthreads(), all stores after; blocks touch
// only their own 64 rows. lane = row, wave owns 32 output cols; W via scalar loads.
__global__ __launch_bounds__(256) void k_gemm(const float* __restrict__ x,
                                              const float* agg,
                                              const float* __restrict__ WtL,
                                              const float* __restrict__ WtR,
                                              const float* __restrict__ bl,
                                              float* out, int N) {
    __shared__ float ssq[256];
    int t = threadIdx.x;
    int wave = __builtin_amdgcn_readfirstlane(t >> 6);
    int lane = t & 63;
    int node0 = blockIdx.x * 64;
    int node = node0 + lane;
    bool valid = node < N;
    int nsafe = valid ? node : (N - 1);
    const float4* xr = (const float4*)(x + (long long)nsafe * D);
    const float4* ar = (const float4*)(agg + (long long)nsafe * D);
    int o0 = wave * 32;

    float acc[32];
#pragma unroll
    for (int j = 0; j < 32; ++j) acc[j] = bl[o0 + j];

    for (int k4 = 0; k4 < 32; ++k4) {
        float4 vx = xr[k4];
        float4 va = ar[k4];
        const float* wl = WtL + (k4 * 4) * D + o0;
        const float* wr = WtR + (k4 * 4) * D + o0;
#pragma unroll
        for (int j = 0; j < 32; ++j) {
            float a = acc[j];
            a = fmaf(va.x, wl[j], fmaf(vx.x, wr[j], a));
            a = fmaf(va.y, wl[D + j], fmaf(vx.y, wr[D + j], a));
            a = fmaf(va.z, wl[2 * D + j], fmaf(vx.z, wr[2 * D + j], a));
            a = fmaf(va.w, wl[3 * D + j], fmaf(vx.w, wr[3 * D + j], a));
            acc[j] = a;
        }
    }

    float s = 0.f;
#pragma unroll
    for (int j = 0; j < 32; ++j) s = fmaf(acc[j], acc[j], s);
    ssq[t] = s;
    __syncthreads();   // also guarantees all agg reads done before in-place stores
    float tot = ssq[lane] + ssq[64 + lane] + ssq[128 + lane] + ssq[192 + lane];
    float scale = 1.0f / fmaxf(sqrtf(tot), 1e-12f);

    if (valid) {
        float4* op = (float4*)(out + (long long)node * D + o0);
#pragma unroll
        for (int j4 = 0; j4 < 8; ++j4) {
            float4 v;
            v.x = acc[j4 * 4 + 0] * scale;
            v.y = acc[j4 * 4 + 1] * scale;
            v.z = acc[j4 * 4 + 2] * scale;
            v.w = acc[j4 * 4 + 3] * scale;
            op[j4] = v;
        }
    }
}

extern "C" void kernel_launch(void* const* d_in, const int* in_sizes, int n_in,
                              void* d_out, int out_size, void* d_ws, size_t ws_size,
                              hipStream_t stream) {
    const float* x  = (const float*)d_in[0];
    const int*   ei = (const int*)d_in[1];
    const float* Wl = (const float*)d_in[2];
    const float* bl = (const float*)d_in[3];
    const float* Wr = (const float*)d_in[4];
    float* out = (float*)d_out;
    const long long E = (long long)in_sizes[1] / 2;

    char* ws = (char*)d_ws;
    int*   flag = (int*)(ws + O_FLAG);
    float* WtL  = (float*)(ws + O_WTL);
    float* WtR  = (float*)(ws + O_WTR);
    float* deg  = (float*)(ws + O_DEG);
    int*   offs = (int*)(ws + O_OFFS);
    int*   curs = (int*)(ws + O_CURS);
    int*   srcs = (int*)(ws + O_SRCS);

    size_t planA_bytes = O_SRCS + (size_t)E * 4;
    bool planA = ws_size >= planA_bytes;

    k_detect<<<1, 64, 0, stream>>>(ei, flag);
    k_transpose<<<(D * D + 255) / 256, 256, 0, stream>>>(Wl, Wr, WtL, WtR);

    int eblocks = (int)((E + 255) / 256);
    if (planA) {
        hipMemsetAsync(ws + O_OFFS, 0, (size_t)(2 * NN + 1) * 4, stream);
        k_hist<<<eblocks, 256, 0, stream>>>(ei, flag, offs, E);
        k_scan<<<1, 1024, 0, stream>>>(offs, NN + 1);
        k_fill<<<eblocks, 256, 0, stream>>>(ei, flag, offs, curs, srcs, E);
        k_agg<<<(NN + 3) / 4, 256, 0, stream>>>(x, offs, srcs, out, NN);
    } else {
        hipMemsetAsync(out, 0, (size_t)NN * D * 4, stream);
        hipMemsetAsync(ws + O_DEG, 0, (size_t)NN * 4, stream);
        k_scatterB<<<(int)((E + 3) / 4), 256, 0, stream>>>(x, ei, flag, out, deg, E);
        k_meanB<<<(int)(((long long)NN * D + 255) / 256), 256, 0, stream>>>(out, deg);
    }
    k_gemm<<<(NN + 63) / 64, 256, 0, stream>>>(x, out, WtL, WtR, bl, out, NN);
}

// Round 2
// 539.109 us; speedup vs baseline: 1.3009x; 1.3009x over previous
//
#include <hip/hip_runtime.h>
#include <stdint.h>

#define NN 100000
#define D 128

// ---- workspace layout (bytes) ----
static const size_t O_FLAG = 0;                               // 4 B (detect flag)
static const size_t O_PART = 256;                             // scan partials (<=256 ints)
static const size_t O_WTL  = O_PART + 1024;
static const size_t O_WTR  = O_WTL + (size_t)D * D * 4;
static const size_t O_DEG  = O_WTR + (size_t)D * D * 4;       // Plan B only
static const size_t O_OFFS = O_DEG + (size_t)NN * 4;
static const size_t O_CURS = O_OFFS + (size_t)(NN + 1) * 4;
static const size_t O_SRCS = O_CURS + (size_t)NN * 4;

// Detect whether edge_index buffer is int64 (odd int32 words zero) or int32.
__global__ void k_detect(const int* __restrict__ ei, int* flag) {
    if (threadIdx.x == 0 && blockIdx.x == 0) {
        int ok = 1;
        for (int j = 0; j < 128; ++j)
            if (ei[2 * j + 1] != 0) { ok = 0; break; }
        *flag = ok;
    }
}

__device__ __forceinline__ int edge_at(const int* ei, long long pos, int is64) {
    return is64 ? ei[2 * pos] : ei[pos];
}

// Transpose both weight matrices: Wt[k][o] = W[o][k]
__global__ void k_transpose(const float* __restrict__ Wl, const float* __restrict__ Wr,
                            float* __restrict__ WtL, float* __restrict__ WtR) {
    int t = blockIdx.x * 256 + threadIdx.x;
    if (t < D * D) {
        int o = t >> 7, k = t & 127;
        WtL[k * D + o] = Wl[t];
        WtR[k * D + o] = Wr[t];
    }
}

// Histogram of dst into offs[d+1]
__global__ void k_hist(const int* __restrict__ ei, const int* __restrict__ flag,
                       int* __restrict__ offs, long long E) {
    long long i = (long long)blockIdx.x * 256 + threadIdx.x;
    if (i >= E) return;
    int is64 = *flag;
    int d = edge_at(ei, E + i, is64);
    atomicAdd(&offs[d + 1], 1);
}

// ---- device-wide scan: 2048 elements per block, 8 per thread ----
#define SCAN_CHUNK 2048
#define SCAN_EPT 8

__global__ __launch_bounds__(256) void k_scan1(const int* __restrict__ a,
                                               int* __restrict__ part, int M) {
    __shared__ int sh[256];
    int t = threadIdx.x;
    int base = blockIdx.x * SCAN_CHUNK + t * SCAN_EPT;
    int s = 0;
#pragma unroll
    for (int i = 0; i < SCAN_EPT; ++i) {
        int idx = base + i;
        if (idx < M) s += a[idx];
    }
    sh[t] = s;
    __syncthreads();
    for (int d = 128; d > 0; d >>= 1) {
        if (t < d) sh[t] += sh[t + d];
        __syncthreads();
    }
    if (t == 0) part[blockIdx.x] = sh[0];
}

__global__ __launch_bounds__(256) void k_scan2(int* __restrict__ part, int B) {
    __shared__ int sh[256];
    int t = threadIdx.x;
    sh[t] = (t < B) ? part[t] : 0;
    __syncthreads();
    for (int d = 1; d < 256; d <<= 1) {
        int u = (t >= d) ? sh[t - d] : 0;
        __syncthreads();
        sh[t] += u;
        __syncthreads();
    }
    if (t < B) part[t] = (t > 0) ? sh[t - 1] : 0;   // exclusive prefix
}

__global__ __launch_bounds__(256) void k_scan3(int* __restrict__ a,
                                               const int* __restrict__ part, int M) {
    __shared__ int sh[256];
    int t = threadIdx.x;
    int base = blockIdx.x * SCAN_CHUNK + t * SCAN_EPT;
    int loc[SCAN_EPT];
    int s = 0;
#pragma unroll
    for (int i = 0; i < SCAN_EPT; ++i) {
        int idx = base + i;
        loc[i] = (idx < M) ? a[idx] : 0;
        s += loc[i];
    }
    sh[t] = s;
    __syncthreads();
    for (int d = 1; d < 256; d <<= 1) {
        int u = (t >= d) ? sh[t - d] : 0;
        __syncthreads();
        sh[t] += u;
        __syncthreads();
    }
    int running = part[blockIdx.x] + ((t > 0) ? sh[t - 1] : 0);
#pragma unroll
    for (int i = 0; i < SCAN_EPT; ++i) {
        int idx = base + i;
        running += loc[i];
        if (idx < M) a[idx] = running;
    }
}

// Fill CSR adjacency: srcs[offs[d] + cursor[d]++] = src
__global__ void k_fill(const int* __restrict__ ei, const int* __restrict__ flag,
                       const int* __restrict__ offs, int* __restrict__ curs,
                       int* __restrict__ srcs, long long E) {
    long long i = (long long)blockIdx.x * 256 + threadIdx.x;
    if (i >= E) return;
    int is64 = *flag;
    int s = edge_at(ei, i, is64);
    int d = edge_at(ei, E + i, is64);
    int pos = offs[d] + atomicAdd(&curs[d], 1);
    srcs[pos] = s;
}

// One wave per node: mean-aggregate neighbor rows. Writes agg into `agg` (= d_out).
__global__ __launch_bounds__(256) void k_agg(const float* __restrict__ x,
                                             const int* __restrict__ offs,
                                             const int* __restrict__ srcs,
                                             float* agg, int N) {
    int lane = threadIdx.x & 63;
    int wid = __builtin_amdgcn_readfirstlane(threadIdx.x >> 6);
    int node = blockIdx.x * 4 + wid;
    if (node >= N) return;
    int e0 = offs[node], e1 = offs[node + 1];
    const float2* x2 = (const float2*)x;
    float ax = 0.f, ay = 0.f;
    int e = e0;
    for (; e + 4 <= e1; e += 4) {
        int s0 = srcs[e], s1 = srcs[e + 1], s2 = srcs[e + 2], s3 = srcs[e + 3];
        float2 v0 = x2[(long long)s0 * 64 + lane];
        float2 v1 = x2[(long long)s1 * 64 + lane];
        float2 v2 = x2[(long long)s2 * 64 + lane];
        float2 v3 = x2[(long long)s3 * 64 + lane];
        ax += v0.x + v1.x + v2.x + v3.x;
        ay += v0.y + v1.y + v2.y + v3.y;
    }
    for (; e < e1; ++e) {
        int s = srcs[e];
        float2 v = x2[(long long)s * 64 + lane];
        ax += v.x; ay += v.y;
    }
    float inv = 1.0f / fmaxf((float)(e1 - e0), 1.0f);
    float2 o; o.x = ax * inv; o.y = ay * inv;
    ((float2*)agg)[(long long)node * 64 + lane] = o;
}

// Plan B: atomic scatter (one wave per edge) then mean.
__global__ __launch_bounds__(256) void k_scatterB(const float* __restrict__ x,
                                                  const int* __restrict__ ei,
                                                  const int* __restrict__ flag,
                                                  float* out, float* deg, long long E) {
    int lane = threadIdx.x & 63;
    long long e = (long long)blockIdx.x * 4 + (threadIdx.x >> 6);
    if (e >= E) return;
    int is64 = *flag;
    int s = edge_at(ei, e, is64);
    int d = edge_at(ei, E + e, is64);
    atomicAdd(&out[(long long)d * D + lane], x[(long long)s * D + lane]);
    atomicAdd(&out[(long long)d * D + 64 + lane], x[(long long)s * D + 64 + lane]);
    if (lane == 0) atomicAdd(&deg[d], 1.0f);
}

__global__ void k_meanB(float* out, const float* __restrict__ deg) {
    long long i = (long long)blockIdx.x * 256 + threadIdx.x;
    if (i >= (long long)NN * D) return;
    out[i] *= 1.0f / fmaxf(deg[i >> 7], 1.0f);
}

// Fused out = agg@Wl^T + b + x@Wr^T, then row L2-normalize. In-place on agg==out:
// all agg reads happen before the __syncthreads(), all stores after; blocks touch
// only their own 64 rows. lane = row, wave owns 32 output cols; W via scalar loads.
__global__ __launch_bounds__(256) void k_gemm(const float* __restrict__ x,
                                              const float* agg,
                                              const float* __restrict__ WtL,
                                              const float* __restrict__ WtR,
                                              const float* __restrict__ bl,
                                              float* out, int N) {
    __shared__ float ssq[256];
    int t = threadIdx.x;
    int wave = __builtin_amdgcn_readfirstlane(t >> 6);
    int lane = t & 63;
    int node0 = blockIdx.x * 64;
    int node = node0 + lane;
    bool valid = node < N;
    int nsafe = valid ? node : (N - 1);
    const float4* xr = (const float4*)(x + (long long)nsafe * D);
    const float4* ar = (const float4*)(agg + (long long)nsafe * D);
    int o0 = wave * 32;

    float acc[32];
#pragma unroll
    for (int j = 0; j < 32; ++j) acc[j] = bl[o0 + j];

    for (int k4 = 0; k4 < 32; ++k4) {
        float4 vx = xr[k4];
        float4 va = ar[k4];
        const float* wl = WtL + (k4 * 4) * D + o0;
        const float* wr = WtR + (k4 * 4) * D + o0;
#pragma unroll
        for (int j = 0; j < 32; ++j) {
            float a = acc[j];
            a = fmaf(va.x, wl[j], fmaf(vx.x, wr[j], a));
            a = fmaf(va.y, wl[D + j], fmaf(vx.y, wr[D + j], a));
            a = fmaf(va.z, wl[2 * D + j], fmaf(vx.z, wr[2 * D + j], a));
            a = fmaf(va.w, wl[3 * D + j], fmaf(vx.w, wr[3 * D + j], a));
            acc[j] = a;
        }
    }

    float s = 0.f;
#pragma unroll
    for (int j = 0; j < 32; ++j) s = fmaf(acc[j], acc[j], s);
    ssq[t] = s;
    __syncthreads();   // also guarantees all agg reads done before in-place stores
    float tot = ssq[lane] + ssq[64 + lane] + ssq[128 + lane] + ssq[192 + lane];
    float scale = 1.0f / fmaxf(sqrtf(tot), 1e-12f);

    if (valid) {
        float4* op = (float4*)(out + (long long)node * D + o0);
#pragma unroll
        for (int j4 = 0; j4 < 8; ++j4) {
            float4 v;
            v.x = acc[j4 * 4 + 0] * scale;
            v.y = acc[j4 * 4 + 1] * scale;
            v.z = acc[j4 * 4 + 2] * scale;
            v.w = acc[j4 * 4 + 3] * scale;
            op[j4] = v;
        }
    }
}

extern "C" void kernel_launch(void* const* d_in, const int* in_sizes, int n_in,
                              void* d_out, int out_size, void* d_ws, size_t ws_size,
                              hipStream_t stream) {
    const float* x  = (const float*)d_in[0];
    const int*   ei = (const int*)d_in[1];
    const float* Wl = (const float*)d_in[2];
    const float* bl = (const float*)d_in[3];
    const float* Wr = (const float*)d_in[4];
    float* out = (float*)d_out;
    const long long E = (long long)in_sizes[1] / 2;

    char* ws = (char*)d_ws;
    int*   flag = (int*)(ws + O_FLAG);
    int*   part = (int*)(ws + O_PART);
    float* WtL  = (float*)(ws + O_WTL);
    float* WtR  = (float*)(ws + O_WTR);
    float* deg  = (float*)(ws + O_DEG);
    int*   offs = (int*)(ws + O_OFFS);
    int*   curs = (int*)(ws + O_CURS);
    int*   srcs = (int*)(ws + O_SRCS);

    size_t planA_bytes = O_SRCS + (size_t)E * 4;
    bool planA = ws_size >= planA_bytes;

    k_detect<<<1, 64, 0, stream>>>(ei, flag);
    k_transpose<<<(D * D + 255) / 256, 256, 0, stream>>>(Wl, Wr, WtL, WtR);

    int eblocks = (int)((E + 255) / 256);
    if (planA) {
        const int M = NN + 1;
        const int B = (M + SCAN_CHUNK - 1) / SCAN_CHUNK;   // 49 blocks, fits k_scan2
        hipMemsetAsync(ws + O_OFFS, 0, (size_t)(2 * NN + 1) * 4, stream);
        k_hist<<<eblocks, 256, 0, stream>>>(ei, flag, offs, E);
        k_scan1<<<B, 256, 0, stream>>>(offs, part, M);
        k_scan2<<<1, 256, 0, stream>>>(part, B);
        k_scan3<<<B, 256, 0, stream>>>(offs, part, M);
        k_fill<<<eblocks, 256, 0, stream>>>(ei, flag, offs, curs, srcs, E);
        k_agg<<<(NN + 3) / 4, 256, 0, stream>>>(x, offs, srcs, out, NN);
    } else {
        hipMemsetAsync(out, 0, (size_t)NN * D * 4, stream);
        hipMemsetAsync(ws + O_DEG, 0, (size_t)NN * 4, stream);
        k_scatterB<<<(int)((E + 3) / 4), 256, 0, stream>>>(x, ei, flag, out, deg, E);
        k_meanB<<<(int)(((long long)NN * D + 255) / 256), 256, 0, stream>>>(out, deg);
    }
    k_gemm<<<(NN + 63) / 64, 256, 0, stream>>>(x, out, WtL, WtR, bl, out, NN);
}

// Round 3
// 505.230 us; speedup vs baseline: 1.3881x; 1.0671x over previous
//
#include <hip/hip_runtime.h>
#include <stdint.h>

#define NN 100000
#define D 128

// ---- workspace layout (bytes) ----
static const size_t O_FLAG = 0;                               // 4 B (detect flag)
static const size_t O_PART = 256;                             // scan partials (<=256 ints)
static const size_t O_WTL  = O_PART + 1024;
static const size_t O_WTR  = O_WTL + (size_t)D * D * 4;
static const size_t O_DEG  = O_WTR + (size_t)D * D * 4;       // Plan B only
static const size_t O_OFFS = O_DEG + (size_t)NN * 4;
static const size_t O_CURS = O_OFFS + (size_t)(NN + 1) * 4;
static const size_t O_SRCS = O_CURS + (size_t)NN * 4;

// Detect whether edge_index buffer is int64 (odd int32 words zero) or int32.
__global__ void k_detect(const int* __restrict__ ei, int* flag) {
    if (threadIdx.x == 0 && blockIdx.x == 0) {
        int ok = 1;
        for (int j = 0; j < 128; ++j)
            if (ei[2 * j + 1] != 0) { ok = 0; break; }
        *flag = ok;
    }
}

__device__ __forceinline__ int edge_at(const int* ei, long long pos, int is64) {
    return is64 ? ei[2 * pos] : ei[pos];
}

// Transpose both weight matrices: Wt[k][o] = W[o][k]
__global__ void k_transpose(const float* __restrict__ Wl, const float* __restrict__ Wr,
                            float* __restrict__ WtL, float* __restrict__ WtR) {
    int t = blockIdx.x * 256 + threadIdx.x;
    if (t < D * D) {
        int o = t >> 7, k = t & 127;
        WtL[k * D + o] = Wl[t];
        WtR[k * D + o] = Wr[t];
    }
}

// Histogram of dst into offs[d+1]
__global__ void k_hist(const int* __restrict__ ei, const int* __restrict__ flag,
                       int* __restrict__ offs, long long E) {
    long long i = (long long)blockIdx.x * 256 + threadIdx.x;
    if (i >= E) return;
    int is64 = *flag;
    int d = edge_at(ei, E + i, is64);
    atomicAdd(&offs[d + 1], 1);
}

// ---- device-wide scan: 2048 elements per block, 8 per thread ----
#define SCAN_CHUNK 2048
#define SCAN_EPT 8

__global__ __launch_bounds__(256) void k_scan1(const int* __restrict__ a,
                                               int* __restrict__ part, int M) {
    __shared__ int sh[256];
    int t = threadIdx.x;
    int base = blockIdx.x * SCAN_CHUNK + t * SCAN_EPT;
    int s = 0;
#pragma unroll
    for (int i = 0; i < SCAN_EPT; ++i) {
        int idx = base + i;
        if (idx < M) s += a[idx];
    }
    sh[t] = s;
    __syncthreads();
    for (int d = 128; d > 0; d >>= 1) {
        if (t < d) sh[t] += sh[t + d];
        __syncthreads();
    }
    if (t == 0) part[blockIdx.x] = sh[0];
}

__global__ __launch_bounds__(256) void k_scan2(int* __restrict__ part, int B) {
    __shared__ int sh[256];
    int t = threadIdx.x;
    sh[t] = (t < B) ? part[t] : 0;
    __syncthreads();
    for (int d = 1; d < 256; d <<= 1) {
        int u = (t >= d) ? sh[t - d] : 0;
        __syncthreads();
        sh[t] += u;
        __syncthreads();
    }
    if (t < B) part[t] = (t > 0) ? sh[t - 1] : 0;   // exclusive prefix
}

__global__ __launch_bounds__(256) void k_scan3(int* __restrict__ a,
                                               const int* __restrict__ part, int M) {
    __shared__ int sh[256];
    int t = threadIdx.x;
    int base = blockIdx.x * SCAN_CHUNK + t * SCAN_EPT;
    int loc[SCAN_EPT];
    int s = 0;
#pragma unroll
    for (int i = 0; i < SCAN_EPT; ++i) {
        int idx = base + i;
        loc[i] = (idx < M) ? a[idx] : 0;
        s += loc[i];
    }
    sh[t] = s;
    __syncthreads();
    for (int d = 1; d < 256; d <<= 1) {
        int u = (t >= d) ? sh[t - d] : 0;
        __syncthreads();
        sh[t] += u;
        __syncthreads();
    }
    int running = part[blockIdx.x] + ((t > 0) ? sh[t - 1] : 0);
#pragma unroll
    for (int i = 0; i < SCAN_EPT; ++i) {
        int idx = base + i;
        running += loc[i];
        if (idx < M) a[idx] = running;
    }
}

// Fill CSR adjacency: srcs[offs[d] + cursor[d]++] = src
__global__ void k_fill(const int* __restrict__ ei, const int* __restrict__ flag,
                       const int* __restrict__ offs, int* __restrict__ curs,
                       int* __restrict__ srcs, long long E) {
    long long i = (long long)blockIdx.x * 256 + threadIdx.x;
    if (i >= E) return;
    int is64 = *flag;
    int s = edge_at(ei, i, is64);
    int d = edge_at(ei, E + i, is64);
    int pos = offs[d] + atomicAdd(&curs[d], 1);
    srcs[pos] = s;
}

// One wave per node: mean-aggregate neighbor rows. Writes agg into `agg` (= d_out).
__global__ __launch_bounds__(256) void k_agg(const float* __restrict__ x,
                                             const int* __restrict__ offs,
                                             const int* __restrict__ srcs,
                                             float* agg, int N) {
    int lane = threadIdx.x & 63;
    int wid = __builtin_amdgcn_readfirstlane(threadIdx.x >> 6);
    int node = blockIdx.x * 4 + wid;
    if (node >= N) return;
    int e0 = offs[node], e1 = offs[node + 1];
    const float2* x2 = (const float2*)x;
    float ax = 0.f, ay = 0.f;
    int e = e0;
    for (; e + 4 <= e1; e += 4) {
        int s0 = srcs[e], s1 = srcs[e + 1], s2 = srcs[e + 2], s3 = srcs[e + 3];
        float2 v0 = x2[(long long)s0 * 64 + lane];
        float2 v1 = x2[(long long)s1 * 64 + lane];
        float2 v2 = x2[(long long)s2 * 64 + lane];
        float2 v3 = x2[(long long)s3 * 64 + lane];
        ax += v0.x + v1.x + v2.x + v3.x;
        ay += v0.y + v1.y + v2.y + v3.y;
    }
    for (; e < e1; ++e) {
        int s = srcs[e];
        float2 v = x2[(long long)s * 64 + lane];
        ax += v.x; ay += v.y;
    }
    float inv = 1.0f / fmaxf((float)(e1 - e0), 1.0f);
    float2 o; o.x = ax * inv; o.y = ay * inv;
    ((float2*)agg)[(long long)node * 64 + lane] = o;
}

// Plan B: atomic scatter (one wave per edge) then mean.
__global__ __launch_bounds__(256) void k_scatterB(const float* __restrict__ x,
                                                  const int* __restrict__ ei,
                                                  const int* __restrict__ flag,
                                                  float* out, float* deg, long long E) {
    int lane = threadIdx.x & 63;
    long long e = (long long)blockIdx.x * 4 + (threadIdx.x >> 6);
    if (e >= E) return;
    int is64 = *flag;
    int s = edge_at(ei, e, is64);
    int d = edge_at(ei, E + e, is64);
    atomicAdd(&out[(long long)d * D + lane], x[(long long)s * D + lane]);
    atomicAdd(&out[(long long)d * D + 64 + lane], x[(long long)s * D + 64 + lane]);
    if (lane == 0) atomicAdd(&deg[d], 1.0f);
}

__global__ void k_meanB(float* out, const float* __restrict__ deg) {
    long long i = (long long)blockIdx.x * 256 + threadIdx.x;
    if (i >= (long long)NN * D) return;
    out[i] *= 1.0f / fmaxf(deg[i >> 7], 1.0f);
}

// Fused out = agg@Wl^T + b + x@Wr^T, then row L2-normalize.
// Block = 256 threads -> 64-row x 128-col tile. Thread = 4 rows x 8 cols.
// Two K-phases share one 64 KB LDS weight buffer; the inter-phase
// __syncthreads() also guarantees all in-place agg reads complete before
// any store (blocks only touch their own 64 rows).
__global__ __launch_bounds__(256) void k_gemm(const float* __restrict__ x,
                                              const float* agg,
                                              const float* __restrict__ WtL,
                                              const float* __restrict__ WtR,
                                              const float* __restrict__ bl,
                                              float* out, int N) {
    __shared__ float Bs[D * D];   // 64 KB: W^T tile, [k][col]
    int t = threadIdx.x;
    int tx = t & 15;              // col group: cols tx*8 .. tx*8+7
    int ty = t >> 4;              // row group: rows row0 .. row0+3
    int row0 = blockIdx.x * 64 + ty * 4;
    int c0 = tx * 8;

    float acc[4][8];
    float4 b0 = *(const float4*)(bl + c0);
    float4 b1 = *(const float4*)(bl + c0 + 4);
#pragma unroll
    for (int r = 0; r < 4; ++r) {
        acc[r][0] = b0.x; acc[r][1] = b0.y; acc[r][2] = b0.z; acc[r][3] = b0.w;
        acc[r][4] = b1.x; acc[r][5] = b1.y; acc[r][6] = b1.z; acc[r][7] = b1.w;
    }

    long long rws[4];
#pragma unroll
    for (int r = 0; r < 4; ++r) {
        int rr = row0 + r;
        rws[r] = (rr < N) ? (long long)rr : (long long)(N - 1);  // clamped for loads
    }

    for (int phase = 0; phase < 2; ++phase) {
        const float* A = phase ? x : agg;
        const float* W = phase ? WtR : WtL;
        if (phase) __syncthreads();   // phase-0 LDS reads + agg reads all done
        // stage W^T (16384 floats) into LDS: 16 float4 per thread, coalesced
#pragma unroll
        for (int i = 0; i < 16; ++i) {
            int idx = t + i * 256;
            ((float4*)Bs)[idx] = ((const float4*)W)[idx];
        }
        __syncthreads();

        const float4* Ar0 = (const float4*)(A + rws[0] * D);
        const float4* Ar1 = (const float4*)(A + rws[1] * D);
        const float4* Ar2 = (const float4*)(A + rws[2] * D);
        const float4* Ar3 = (const float4*)(A + rws[3] * D);

#pragma unroll 2
        for (int k4 = 0; k4 < 32; ++k4) {
            float4 av[4];
            av[0] = Ar0[k4]; av[1] = Ar1[k4]; av[2] = Ar2[k4]; av[3] = Ar3[k4];
#pragma unroll
            for (int kk = 0; kk < 4; ++kk) {
                int k = k4 * 4 + kk;
                float4 w0 = *(const float4*)&Bs[k * D + c0];
                float4 w1 = *(const float4*)&Bs[k * D + c0 + 4];
#pragma unroll
                for (int r = 0; r < 4; ++r) {
                    float a = (kk == 0) ? av[r].x : (kk == 1) ? av[r].y
                             : (kk == 2) ? av[r].z : av[r].w;
                    acc[r][0] = fmaf(a, w0.x, acc[r][0]);
                    acc[r][1] = fmaf(a, w0.y, acc[r][1]);
                    acc[r][2] = fmaf(a, w0.z, acc[r][2]);
                    acc[r][3] = fmaf(a, w0.w, acc[r][3]);
                    acc[r][4] = fmaf(a, w1.x, acc[r][4]);
                    acc[r][5] = fmaf(a, w1.y, acc[r][5]);
                    acc[r][6] = fmaf(a, w1.z, acc[r][6]);
                    acc[r][7] = fmaf(a, w1.w, acc[r][7]);
                }
            }
        }
    }

    // Row L2-norm: partial sumsq over this thread's 8 cols, then butterfly
    // across the 16 col-threads (same wave, lanes (lane&~15)+0..15).
#pragma unroll
    for (int r = 0; r < 4; ++r) {
        float s = 0.f;
#pragma unroll
        for (int j = 0; j < 8; ++j) s = fmaf(acc[r][j], acc[r][j], s);
        s += __shfl_xor(s, 1, 64);
        s += __shfl_xor(s, 2, 64);
        s += __shfl_xor(s, 4, 64);
        s += __shfl_xor(s, 8, 64);
        float scale = 1.0f / fmaxf(sqrtf(s), 1e-12f);
        int rr = row0 + r;
        if (rr < N) {
            float4 v0, v1;
            v0.x = acc[r][0] * scale; v0.y = acc[r][1] * scale;
            v0.z = acc[r][2] * scale; v0.w = acc[r][3] * scale;
            v1.x = acc[r][4] * scale; v1.y = acc[r][5] * scale;
            v1.z = acc[r][6] * scale; v1.w = acc[r][7] * scale;
            float4* op = (float4*)(out + (long long)rr * D + c0);
            op[0] = v0; op[1] = v1;
        }
    }
}

extern "C" void kernel_launch(void* const* d_in, const int* in_sizes, int n_in,
                              void* d_out, int out_size, void* d_ws, size_t ws_size,
                              hipStream_t stream) {
    const float* x  = (const float*)d_in[0];
    const int*   ei = (const int*)d_in[1];
    const float* Wl = (const float*)d_in[2];
    const float* bl = (const float*)d_in[3];
    const float* Wr = (const float*)d_in[4];
    float* out = (float*)d_out;
    const long long E = (long long)in_sizes[1] / 2;

    char* ws = (char*)d_ws;
    int*   flag = (int*)(ws + O_FLAG);
    int*   part = (int*)(ws + O_PART);
    float* WtL  = (float*)(ws + O_WTL);
    float* WtR  = (float*)(ws + O_WTR);
    float* deg  = (float*)(ws + O_DEG);
    int*   offs = (int*)(ws + O_OFFS);
    int*   curs = (int*)(ws + O_CURS);
    int*   srcs = (int*)(ws + O_SRCS);

    size_t planA_bytes = O_SRCS + (size_t)E * 4;
    bool planA = ws_size >= planA_bytes;

    k_detect<<<1, 64, 0, stream>>>(ei, flag);
    k_transpose<<<(D * D + 255) / 256, 256, 0, stream>>>(Wl, Wr, WtL, WtR);

    int eblocks = (int)((E + 255) / 256);
    if (planA) {
        const int M = NN + 1;
        const int B = (M + SCAN_CHUNK - 1) / SCAN_CHUNK;   // 49 blocks, fits k_scan2
        hipMemsetAsync(ws + O_OFFS, 0, (size_t)(2 * NN + 1) * 4, stream);
        k_hist<<<eblocks, 256, 0, stream>>>(ei, flag, offs, E);
        k_scan1<<<B, 256, 0, stream>>>(offs, part, M);
        k_scan2<<<1, 256, 0, stream>>>(part, B);
        k_scan3<<<B, 256, 0, stream>>>(offs, part, M);
        k_fill<<<eblocks, 256, 0, stream>>>(ei, flag, offs, curs, srcs, E);
        k_agg<<<(NN + 3) / 4, 256, 0, stream>>>(x, offs, srcs, out, NN);
    } else {
        hipMemsetAsync(out, 0, (size_t)NN * D * 4, stream);
        hipMemsetAsync(ws + O_DEG, 0, (size_t)NN * 4, stream);
        k_scatterB<<<(int)((E + 3) / 4), 256, 0, stream>>>(x, ei, flag, out, deg, E);
        k_meanB<<<(int)(((long long)NN * D + 255) / 256), 256, 0, stream>>>(out, deg);
    }
    k_gemm<<<(NN + 63) / 64, 256, 0, stream>>>(x, out, WtL, WtR, bl, out, NN);
}